// Round 13
// baseline (53.663 us; speedup 1.0000x reference)
//
#include <hip/hip_runtime.h>

// DynamicKoopmanOperator — R13: R12 + unroll-4 W-load loops (last live lever).
// Store phase: proven pattern-invariant (NT/chains/fronts/occupancy all
// neutral or worse); 6.0-6.4 TB/s ~ 91% of fill's 7.08 ceiling. Done.
// MLP: 6.5us vs 3.2us L2 floor; gap = dependent-load stalls (unroll-2 keeps
// only 8 loads in flight). unroll-4 -> 16 in flight (wv regs 64 VGPR, fits
// the 2-wave/SIMD 256-VGPR budget).

#define DT_CONST 0.01f

typedef float f32x4 __attribute__((ext_vector_type(4)));

constexpr int KDIM   = 256;
constexpr int AROWS  = 4;               // batch rows per block -> 256 blocks
constexpr int KSPLIT = 8;               // k-slices (= wave id)
constexpr int KSLICE = KDIM / KSPLIT;   // 32 k's per slice

// ---------------- fused kernel ----------------------------------------------
__global__ __launch_bounds__(512) void koopman_fused(
    const float* __restrict__ x,  const float* __restrict__ W1,
    const float* __restrict__ b1, const float* __restrict__ W2,
    const float* __restrict__ b2, float* __restrict__ out, int T)
{
    __shared__ alignas(16) float xs[AROWS][KDIM];              // 4 KiB
    __shared__ alignas(16) float hs[AROWS][KDIM];              // 4 KiB
    __shared__ alignas(16) float coef[AROWS][KDIM];            // 4 KiB
    __shared__ alignas(16) float part[KSPLIT][AROWS][KDIM];    // 32 KiB

    const int tid = threadIdx.x;
    const int jg  = tid & 63;           // column group: cols [jg*4, jg*4+4)
    const int ks  = tid >> 6;           // k-slice 0..7 (wave-uniform)
    const int b0  = blockIdx.x * AROWS;

    // stage x rows (vectorized, 256 f32x4)
    {
        const f32x4* xg = reinterpret_cast<const f32x4*>(x + (size_t)b0 * KDIM);
        f32x4* xl = reinterpret_cast<f32x4*>(&xs[0][0]);
        for (int i = tid; i < AROWS * KDIM / 4; i += 512) xl[i] = xg[i];
    }
    __syncthreads();

    f32x4 acc[AROWS];

    // ---- GEMM 1: h = tanh(x @ W1 + b1) ----
    {
#pragma unroll
        for (int r = 0; r < AROWS; ++r) acc[r] = (f32x4){0.f, 0.f, 0.f, 0.f};
        const float* wbase = W1 + (size_t)ks * KSLICE * KDIM + jg * 4;
#pragma unroll 4
        for (int k4 = 0; k4 < KSLICE / 4; ++k4) {
            f32x4 wv[4];
#pragma unroll
            for (int i = 0; i < 4; ++i)      // 4x global dwordx4, coalesced
                wv[i] = *reinterpret_cast<const f32x4*>(wbase + (size_t)(k4 * 4 + i) * KDIM);
            f32x4 xv[AROWS];
#pragma unroll
            for (int r = 0; r < AROWS; ++r)  // uniform b128 broadcast
                xv[r] = *reinterpret_cast<const f32x4*>(&xs[r][ks * KSLICE + k4 * 4]);
#pragma unroll
            for (int i = 0; i < 4; ++i)
#pragma unroll
                for (int r = 0; r < AROWS; ++r)
                    acc[r] += wv[i] * xv[r][i];      // vec FMA
        }
#pragma unroll
        for (int r = 0; r < AROWS; ++r)
            *reinterpret_cast<f32x4*>(&part[ks][r][jg * 4]) = acc[r];
    }
    __syncthreads();
    // reduce ksplit partials + bias + tanh -> hs  (f32x4)
    if (tid < AROWS * KDIM / 4) {
        const int r = tid >> 6, j4 = tid & 63;
        f32x4 ssum = *reinterpret_cast<const f32x4*>(b1 + j4 * 4);
#pragma unroll
        for (int s = 0; s < KSPLIT; ++s)
            ssum += *reinterpret_cast<const f32x4*>(&part[s][r][j4 * 4]);
        f32x4 hv = { tanhf(ssum.x), tanhf(ssum.y), tanhf(ssum.z), tanhf(ssum.w) };
        *reinterpret_cast<f32x4*>(&hs[r][j4 * 4]) = hv;
    }
    __syncthreads();

    // ---- GEMM 2: eigs = h @ W2 + b2 ----
    {
#pragma unroll
        for (int r = 0; r < AROWS; ++r) acc[r] = (f32x4){0.f, 0.f, 0.f, 0.f};
        const float* wbase = W2 + (size_t)ks * KSLICE * KDIM + jg * 4;
#pragma unroll 4
        for (int k4 = 0; k4 < KSLICE / 4; ++k4) {
            f32x4 wv[4];
#pragma unroll
            for (int i = 0; i < 4; ++i)
                wv[i] = *reinterpret_cast<const f32x4*>(wbase + (size_t)(k4 * 4 + i) * KDIM);
            f32x4 hv[AROWS];
#pragma unroll
            for (int r = 0; r < AROWS; ++r)
                hv[r] = *reinterpret_cast<const f32x4*>(&hs[r][ks * KSLICE + k4 * 4]);
#pragma unroll
            for (int i = 0; i < 4; ++i)
#pragma unroll
                for (int r = 0; r < AROWS; ++r)
                    acc[r] += wv[i] * hv[r][i];
        }
#pragma unroll
        for (int r = 0; r < AROWS; ++r)
            *reinterpret_cast<f32x4*>(&part[ks][r][jg * 4]) = acc[r];
    }
    __syncthreads();
    // reduce + bias, pre-scale by dt -> coef (f32x4)
    if (tid < AROWS * KDIM / 4) {
        const int r = tid >> 6, j4 = tid & 63;
        f32x4 ssum = *reinterpret_cast<const f32x4*>(b2 + j4 * 4);
#pragma unroll
        for (int s = 0; s < KSPLIT; ++s)
            ssum += *reinterpret_cast<const f32x4*>(&part[s][r][j4 * 4]);
        *reinterpret_cast<f32x4*>(&coef[r][j4 * 4]) = ssum * DT_CONST;
    }
    __syncthreads();                        // last barrier

    // ---- Phase 2: rollout. Waves 0-3: one FULL row each; t0=0 -> seed z=x.
    const int wave = tid >> 6;
    if (wave >= AROWS) return;              // waves 4-7 retire

    const int lane = tid & 63;              // lane = 2 pairs (4 elems)
    const int r    = wave;                  // row within block
    const int b    = b0 + r;

    const f32x4 c  = *reinterpret_cast<const f32x4*>(&coef[r][lane * 4]);
    const f32x4 xv = *reinterpret_cast<const f32x4*>(&xs[r][lane * 4]);
    // c = (mu0*dt, om0*dt, mu1*dt, om1*dt)

    float z0 = xv.x, z1 = xv.y, z2 = xv.z, z3 = xv.w;

    float s, co, e;
    e = expf(c.x); sincosf(c.y, &s, &co);
    const float a0 = e * co, g0 = e * s;
    e = expf(c.z); sincosf(c.w, &s, &co);
    const float a1 = e * co, g1 = e * s;

    f32x4* orow = reinterpret_cast<f32x4*>(out + (size_t)b * T * KDIM) + lane;
#pragma unroll 4
    for (int t = 0; t < T; ++t) {
        float n0 = a0 * z0 - g0 * z1;
        float n1 = g0 * z0 + a0 * z1;
        float n2 = a1 * z2 - g1 * z3;
        float n3 = g1 * z2 + a1 * z3;
        f32x4 v = { n0, n1, n2, n3 };
        *orow = v;                           // plain store, through L2
        orow += KDIM / 4;                    // next timestep, 1 KiB row/wave
        z0 = n0; z1 = n1; z2 = n2; z3 = n3;
    }
}

// ---------------- launcher ---------------------------------------------------
extern "C" void kernel_launch(void* const* d_in, const int* in_sizes, int n_in,
                              void* d_out, int out_size, void* d_ws, size_t ws_size,
                              hipStream_t stream) {
    const float* x  = (const float*)d_in[0];
    const float* W1 = (const float*)d_in[1];
    const float* b1 = (const float*)d_in[2];
    const float* W2 = (const float*)d_in[3];
    const float* b2 = (const float*)d_in[4];

    const int Kd = in_sizes[2];                 // 256
    const int Bb = in_sizes[0] / Kd;            // 1024
    const int T  = out_size / (Bb * Kd);        // 256

    float* out = (float*)d_out;

    koopman_fused<<<Bb / AROWS, 512, 0, stream>>>(x, W1, b1, W2, b2, out, T);
}

// Round 14
// 52.416 us; speedup vs baseline: 1.0238x; 1.0238x over previous
//
#include <hip/hip_runtime.h>

// DynamicKoopmanOperator — R14: revert to R12 (best: 52.4us).
// R13's unroll-4 regressed (+1.2us): VGPR/scheduling cost > latency coverage.
// Final ledger: launch ~1.4 + MLP ~6.5 (L2-latency bound at 2 waves/SIMD;
// staging/scalar/width/unroll all tested) + store ~44 @ 6.0-6.4 TB/s (91% of
// fill's 7.08 ceiling; NT/chain-ILP/front-count/occupancy all tested neutral
// or worse). This kernel is at the practical roofline.

#define DT_CONST 0.01f

typedef float f32x4 __attribute__((ext_vector_type(4)));

constexpr int KDIM   = 256;
constexpr int AROWS  = 4;               // batch rows per block -> 256 blocks
constexpr int KSPLIT = 8;               // k-slices (= wave id)
constexpr int KSLICE = KDIM / KSPLIT;   // 32 k's per slice

// ---------------- fused kernel ----------------------------------------------
__global__ __launch_bounds__(512) void koopman_fused(
    const float* __restrict__ x,  const float* __restrict__ W1,
    const float* __restrict__ b1, const float* __restrict__ W2,
    const float* __restrict__ b2, float* __restrict__ out, int T)
{
    __shared__ alignas(16) float xs[AROWS][KDIM];              // 4 KiB
    __shared__ alignas(16) float hs[AROWS][KDIM];              // 4 KiB
    __shared__ alignas(16) float coef[AROWS][KDIM];            // 4 KiB
    __shared__ alignas(16) float part[KSPLIT][AROWS][KDIM];    // 32 KiB

    const int tid = threadIdx.x;
    const int jg  = tid & 63;           // column group: cols [jg*4, jg*4+4)
    const int ks  = tid >> 6;           // k-slice 0..7 (wave-uniform)
    const int b0  = blockIdx.x * AROWS;

    // stage x rows (vectorized, 256 f32x4)
    {
        const f32x4* xg = reinterpret_cast<const f32x4*>(x + (size_t)b0 * KDIM);
        f32x4* xl = reinterpret_cast<f32x4*>(&xs[0][0]);
        for (int i = tid; i < AROWS * KDIM / 4; i += 512) xl[i] = xg[i];
    }
    __syncthreads();

    f32x4 acc[AROWS];

    // ---- GEMM 1: h = tanh(x @ W1 + b1) ----
    {
#pragma unroll
        for (int r = 0; r < AROWS; ++r) acc[r] = (f32x4){0.f, 0.f, 0.f, 0.f};
        const float* wbase = W1 + (size_t)ks * KSLICE * KDIM + jg * 4;
#pragma unroll 2
        for (int k4 = 0; k4 < KSLICE / 4; ++k4) {
            f32x4 wv[4];
#pragma unroll
            for (int i = 0; i < 4; ++i)      // 4x global dwordx4, coalesced
                wv[i] = *reinterpret_cast<const f32x4*>(wbase + (size_t)(k4 * 4 + i) * KDIM);
            f32x4 xv[AROWS];
#pragma unroll
            for (int r = 0; r < AROWS; ++r)  // uniform b128 broadcast
                xv[r] = *reinterpret_cast<const f32x4*>(&xs[r][ks * KSLICE + k4 * 4]);
#pragma unroll
            for (int i = 0; i < 4; ++i)
#pragma unroll
                for (int r = 0; r < AROWS; ++r)
                    acc[r] += wv[i] * xv[r][i];      // vec FMA
        }
#pragma unroll
        for (int r = 0; r < AROWS; ++r)
            *reinterpret_cast<f32x4*>(&part[ks][r][jg * 4]) = acc[r];
    }
    __syncthreads();
    // reduce ksplit partials + bias + tanh -> hs  (f32x4)
    if (tid < AROWS * KDIM / 4) {
        const int r = tid >> 6, j4 = tid & 63;
        f32x4 ssum = *reinterpret_cast<const f32x4*>(b1 + j4 * 4);
#pragma unroll
        for (int s = 0; s < KSPLIT; ++s)
            ssum += *reinterpret_cast<const f32x4*>(&part[s][r][j4 * 4]);
        f32x4 hv = { tanhf(ssum.x), tanhf(ssum.y), tanhf(ssum.z), tanhf(ssum.w) };
        *reinterpret_cast<f32x4*>(&hs[r][j4 * 4]) = hv;
    }
    __syncthreads();

    // ---- GEMM 2: eigs = h @ W2 + b2 ----
    {
#pragma unroll
        for (int r = 0; r < AROWS; ++r) acc[r] = (f32x4){0.f, 0.f, 0.f, 0.f};
        const float* wbase = W2 + (size_t)ks * KSLICE * KDIM + jg * 4;
#pragma unroll 2
        for (int k4 = 0; k4 < KSLICE / 4; ++k4) {
            f32x4 wv[4];
#pragma unroll
            for (int i = 0; i < 4; ++i)
                wv[i] = *reinterpret_cast<const f32x4*>(wbase + (size_t)(k4 * 4 + i) * KDIM);
            f32x4 hv[AROWS];
#pragma unroll
            for (int r = 0; r < AROWS; ++r)
                hv[r] = *reinterpret_cast<const f32x4*>(&hs[r][ks * KSLICE + k4 * 4]);
#pragma unroll
            for (int i = 0; i < 4; ++i)
#pragma unroll
                for (int r = 0; r < AROWS; ++r)
                    acc[r] += wv[i] * hv[r][i];
        }
#pragma unroll
        for (int r = 0; r < AROWS; ++r)
            *reinterpret_cast<f32x4*>(&part[ks][r][jg * 4]) = acc[r];
    }
    __syncthreads();
    // reduce + bias, pre-scale by dt -> coef (f32x4)
    if (tid < AROWS * KDIM / 4) {
        const int r = tid >> 6, j4 = tid & 63;
        f32x4 ssum = *reinterpret_cast<const f32x4*>(b2 + j4 * 4);
#pragma unroll
        for (int s = 0; s < KSPLIT; ++s)
            ssum += *reinterpret_cast<const f32x4*>(&part[s][r][j4 * 4]);
        *reinterpret_cast<f32x4*>(&coef[r][j4 * 4]) = ssum * DT_CONST;
    }
    __syncthreads();                        // last barrier

    // ---- Phase 2: rollout. Waves 0-3: one FULL row each; t0=0 -> seed z=x.
    const int wave = tid >> 6;
    if (wave >= AROWS) return;              // waves 4-7 retire

    const int lane = tid & 63;              // lane = 2 pairs (4 elems)
    const int r    = wave;                  // row within block
    const int b    = b0 + r;

    const f32x4 c  = *reinterpret_cast<const f32x4*>(&coef[r][lane * 4]);
    const f32x4 xv = *reinterpret_cast<const f32x4*>(&xs[r][lane * 4]);
    // c = (mu0*dt, om0*dt, mu1*dt, om1*dt)

    float z0 = xv.x, z1 = xv.y, z2 = xv.z, z3 = xv.w;

    float s, co, e;
    e = expf(c.x); sincosf(c.y, &s, &co);
    const float a0 = e * co, g0 = e * s;
    e = expf(c.z); sincosf(c.w, &s, &co);
    const float a1 = e * co, g1 = e * s;

    f32x4* orow = reinterpret_cast<f32x4*>(out + (size_t)b * T * KDIM) + lane;
#pragma unroll 4
    for (int t = 0; t < T; ++t) {
        float n0 = a0 * z0 - g0 * z1;
        float n1 = g0 * z0 + a0 * z1;
        float n2 = a1 * z2 - g1 * z3;
        float n3 = g1 * z2 + a1 * z3;
        f32x4 v = { n0, n1, n2, n3 };
        *orow = v;                           // plain store, through L2
        orow += KDIM / 4;                    // next timestep, 1 KiB row/wave
        z0 = n0; z1 = n1; z2 = n2; z3 = n3;
    }
}

// ---------------- launcher ---------------------------------------------------
extern "C" void kernel_launch(void* const* d_in, const int* in_sizes, int n_in,
                              void* d_out, int out_size, void* d_ws, size_t ws_size,
                              hipStream_t stream) {
    const float* x  = (const float*)d_in[0];
    const float* W1 = (const float*)d_in[1];
    const float* b1 = (const float*)d_in[2];
    const float* W2 = (const float*)d_in[3];
    const float* b2 = (const float*)d_in[4];

    const int Kd = in_sizes[2];                 // 256
    const int Bb = in_sizes[0] / Kd;            // 1024
    const int T  = out_size / (Bb * Kd);        // 256

    float* out = (float*)d_out;

    koopman_fused<<<Bb / AROWS, 512, 0, stream>>>(x, W1, b1, W2, b2, out, T);
}